// Round 6
// baseline (341.355 us; speedup 1.0000x reference)
//
#include <hip/hip_runtime.h>

// FastFood layer: out = (1/sqrt(D)) * [cos(w), sin(w)] + bias
//   w = (1/sqrt(D)) * S ⊙ FWHT( G ⊙ Perm( FWHT( B ⊙ x ) ) )
//
// High-occupancy design: 8 regs/lane, 2 waves per stack, block = 256 thr
// = 2 stacks of one row. grid = 2 blocks/row. Element mapping:
//   e[1:0] = reg[1:0], e[8] = reg[2], e[7:2] = lane[5:0], e[9] = wave-pair bit w
// Per-wave state halves vs the 16-reg design (~50-60 VGPR -> 6-8 waves/SIMD,
// LDS 8 KB/block), per-wave dependent chains halve. The cross-wave e9 stage
// is FREE: stages commute, so it is fused into the global load (FWHT#1:
// v = sgW*B[e]x[e] + B[e^512]x[e^512]) and into the permutation gather
// (FWHT#2: gather both halves from LDS, combine in the same fma). Partner
// loads are L1/L2 hits (same cache lines as the partner wave's own loads).
//
// Cross-lane stages (all verified on HW in the round-5 kernel):
//   lane^1 : DPP quad_perm [1,0,3,2]   lane^2 : DPP quad_perm [2,3,0,1]
//   lane^4 : ds_swizzle 0x101F         lane^8 : DPP row_ror:8
//   lane^16: ds_swizzle 0x401F         lane^32: __shfl_xor(v,32)
// Butterfly: v = fma(sign, v, partner), sign = -1 where the stage bit is set.

#define FF_D 1024
#define FF_STACK 4
#define FF_NT 256

#define SWZF(vf, OFF) \
    __int_as_float(__builtin_amdgcn_ds_swizzle(__float_as_int(vf), (OFF)))

// DPP move: partner = src lane permuted by CTRL; disabled-lane fallback = identity
#define DPPF(vf, CTRL) \
    __int_as_float(__builtin_amdgcn_update_dpp( \
        __float_as_int(vf), __float_as_int(vf), (CTRL), 0xF, 0xF, false))

// in-register butterfly on reg-bit m (8 regs)
#define STAGE_BIT8(vv, m) { \
    _Pragma("unroll") \
    for (int i_ = 0; i_ < 8; ++i_) \
        if (!(i_ & (m))) { \
            float s_ = vv[i_] + vv[i_ | (m)]; \
            float d_ = vv[i_] - vv[i_ | (m)]; \
            vv[i_] = s_; vv[i_ | (m)] = d_; \
        } \
}

// cross-lane butterfly via DPP (VALU pipe)
#define STAGE_DPP8(vv, CTRL, sgn) { \
    float p_[8]; \
    _Pragma("unroll") \
    for (int i_ = 0; i_ < 8; ++i_) p_[i_] = DPPF(vv[i_], CTRL); \
    _Pragma("unroll") \
    for (int i_ = 0; i_ < 8; ++i_) vv[i_] = __builtin_fmaf(sgn, vv[i_], p_[i_]); \
}

// cross-lane butterfly via ds_swizzle (literal BitMode offset OFF)
#define STAGE_SWZ8(vv, OFF, sgn) { \
    float p_[8]; \
    _Pragma("unroll") \
    for (int i_ = 0; i_ < 8; ++i_) p_[i_] = SWZF(vv[i_], OFF); \
    _Pragma("unroll") \
    for (int i_ = 0; i_ < 8; ++i_) vv[i_] = __builtin_fmaf(sgn, vv[i_], p_[i_]); \
}

// cross-lane butterfly on lane-xor 32
#define STAGE_X32_8(vv, sgn) { \
    float p_[8]; \
    _Pragma("unroll") \
    for (int i_ = 0; i_ < 8; ++i_) p_[i_] = __shfl_xor(vv[i_], 32, 64); \
    _Pragma("unroll") \
    for (int i_ = 0; i_ < 8; ++i_) vv[i_] = __builtin_fmaf(sgn, vv[i_], p_[i_]); \
}

// 9 remaining FWHT stages (e9 fused into load / gather)
#define FWHT9(vv) { \
    STAGE_BIT8(vv, 1) STAGE_BIT8(vv, 2) STAGE_BIT8(vv, 4) \
    STAGE_DPP8(vv, 0xB1, sgL1)    /* e2: lane^1  quad_perm [1,0,3,2] */ \
    STAGE_DPP8(vv, 0x4E, sgL2)    /* e3: lane^2  quad_perm [2,3,0,1] */ \
    STAGE_SWZ8(vv, 0x101F, sgL4)  /* e4: lane^4  ds_swizzle          */ \
    STAGE_DPP8(vv, 0x128, sgL8)   /* e5: lane^8  row_ror:8           */ \
    STAGE_SWZ8(vv, 0x401F, sgL16) /* e6: lane^16 ds_swizzle          */ \
    STAGE_X32_8(vv, sgL32)        /* e7: lane^32                     */ \
}

// sincos epilogue for one element
#define CS1(val, sc, bc, bs, oC, oS) { \
    const float tr_ = __builtin_amdgcn_fractf((val) * ((sc) * karg)); \
    oC = __builtin_amdgcn_cosf(tr_) * kout + (bc); \
    oS = __builtin_amdgcn_sinf(tr_) * kout + (bs); \
}

__global__ __launch_bounds__(FF_NT, 6) void fastfood_kernel(
    const float* __restrict__ x,
    const float* __restrict__ Bs,
    const float* __restrict__ G,
    const float* __restrict__ S,
    const float* __restrict__ bias,
    const int*   __restrict__ P,
    float* __restrict__ out)
{
    __shared__ float park[2][FF_D];          // 8 KB: one 1024-row per stack
    const int tid  = threadIdx.x;
    const int lane = tid & 63;
    const int wave = tid >> 6;
    const int w    = wave & 1;               // e9 half handled by this wave
    const int sl   = wave >> 1;              // stack-local within block (0/1)
    const int row  = blockIdx.x >> 1;
    const int s    = ((blockIdx.x & 1) << 1) | sl;   // global stack 0..3
    const int sb   = s << 10;

    const float sgW   = w          ? -1.0f : 1.0f;   // fused-e9 sign
    const float sgL1  = (lane & 1)  ? -1.0f : 1.0f;
    const float sgL2  = (lane & 2)  ? -1.0f : 1.0f;
    const float sgL4  = (lane & 4)  ? -1.0f : 1.0f;
    const float sgL8  = (lane & 8)  ? -1.0f : 1.0f;
    const float sgL16 = (lane & 16) ? -1.0f : 1.0f;
    const float sgL32 = (lane & 32) ? -1.0f : 1.0f;

    const float kout = 0.03125f;                      // 1/sqrt(1024)
    const float karg = 0.03125f * 0.15915494309f;     // /(2*pi): revolutions

    float v[8];

    // ---- load x (both e9 halves), fuse diag B and the e9 butterfly ----
    const long long xb = (long long)row << 10;
    #pragma unroll
    for (int q = 0; q < 2; ++q) {
        const int own = (w << 9) | (q << 8) | (lane << 2);
        const int par = own ^ 512;
        const float4 xo = *(const float4*)&x[xb + own];
        const float4 xp = *(const float4*)&x[xb + par];
        const float4 bo = *(const float4*)&Bs[sb + own];
        const float4 bp = *(const float4*)&Bs[sb + par];
        v[4*q+0] = __builtin_fmaf(sgW, bo.x * xo.x, bp.x * xp.x);
        v[4*q+1] = __builtin_fmaf(sgW, bo.y * xo.y, bp.y * xp.y);
        v[4*q+2] = __builtin_fmaf(sgW, bo.z * xo.z, bp.z * xp.z);
        v[4*q+3] = __builtin_fmaf(sgW, bo.w * xo.w, bp.w * xp.w);
    }

    // ---------- FWHT #1: remaining 9 stages ----------
    FWHT9(v)

    // ---- prefetch P,G (own + partner halves) before the park ----
    int4   po[2], pp[2];
    float4 go[2], gp[2];
    #pragma unroll
    for (int q = 0; q < 2; ++q) {
        const int own = (w << 9) | (q << 8) | (lane << 2);
        const int par = own ^ 512;
        po[q] = *(const int4*)&P[sb + own];
        pp[q] = *(const int4*)&P[sb + par];
        go[q] = *(const float4*)&G[sb + own];
        gp[q] = *(const float4*)&G[sb + par];
    }

    // ---- park this wave's half of the stack row ----
    #pragma unroll
    for (int q = 0; q < 2; ++q) {
        const int own = (w << 9) | (q << 8) | (lane << 2);
        *(float4*)&park[sl][own] = make_float4(v[4*q], v[4*q+1], v[4*q+2], v[4*q+3]);
    }
    __syncthreads();

    // ---- permutation gather + diag G, fused with FWHT#2's e9 butterfly ----
    #pragma unroll
    for (int q = 0; q < 2; ++q) {
        v[4*q+0] = __builtin_fmaf(sgW, park[sl][po[q].x & (FF_D-1)] * go[q].x,
                                       park[sl][pp[q].x & (FF_D-1)] * gp[q].x);
        v[4*q+1] = __builtin_fmaf(sgW, park[sl][po[q].y & (FF_D-1)] * go[q].y,
                                       park[sl][pp[q].y & (FF_D-1)] * gp[q].y);
        v[4*q+2] = __builtin_fmaf(sgW, park[sl][po[q].z & (FF_D-1)] * go[q].z,
                                       park[sl][pp[q].z & (FF_D-1)] * gp[q].z);
        v[4*q+3] = __builtin_fmaf(sgW, park[sl][po[q].w & (FF_D-1)] * go[q].w,
                                       park[sl][pp[q].w & (FF_D-1)] * gp[q].w);
    }

    // ---------- FWHT #2: remaining 9 stages ----------
    FWHT9(v)

    // ---------- epilogue: scale, sincos, store (1 KB/instr coalesced) ----------
    const long long ob = (long long)row << 13;        // row * 8192
    #pragma unroll
    for (int q = 0; q < 2; ++q) {
        const int j = sb + ((w << 9) | (q << 8) | (lane << 2));
        const float4 s4  = *(const float4*)&S[j];
        const float4 bc4 = *(const float4*)&bias[j];
        const float4 bs4 = *(const float4*)&bias[FF_STACK * FF_D + j];
        float4 oc, os;
        CS1(v[4*q+0], s4.x, bc4.x, bs4.x, oc.x, os.x)
        CS1(v[4*q+1], s4.y, bc4.y, bs4.y, oc.y, os.y)
        CS1(v[4*q+2], s4.z, bc4.z, bs4.z, oc.z, os.z)
        CS1(v[4*q+3], s4.w, bc4.w, bs4.w, oc.w, os.w)
        *(float4*)&out[ob + j] = oc;
        *(float4*)&out[ob + FF_STACK * FF_D + j] = os;
    }
}

extern "C" void kernel_launch(void* const* d_in, const int* in_sizes, int n_in,
                              void* d_out, int out_size, void* d_ws, size_t ws_size,
                              hipStream_t stream) {
    // setup_inputs order: x, B, G, S, bias, H, P   (H unused: FWHT instead)
    const float* x    = (const float*)d_in[0];
    const float* B    = (const float*)d_in[1];
    const float* G    = (const float*)d_in[2];
    const float* S    = (const float*)d_in[3];
    const float* bias = (const float*)d_in[4];
    const int*   P    = (const int*)d_in[6];
    float* out = (float*)d_out;

    const int n_rows = in_sizes[0] / FF_D;   // 8192
    fastfood_kernel<<<n_rows * 2, FF_NT, 0, stream>>>(x, B, G, S, bias, P, out);
}

// Round 7
// 332.232 us; speedup vs baseline: 1.0275x; 1.0275x over previous
//
#include <hip/hip_runtime.h>

// FastFood layer: out = (1/sqrt(D)) * [cos(w), sin(w)] + bias
//   w = (1/sqrt(D)) * S ⊙ FWHT( G ⊙ Perm( FWHT( B ⊙ x ) ) )
//
// Four-rows-per-wave design: block = 256 thr (4 waves), wave w = stack w for
// FOUR consecutive rows; grid = n_rows/4. Each wave carries four independent
// dependency chains (a0..a3). Phase structure:
//   load 4 rows (deep vmem pipeline) -> FWHT#1 x4 ->
//   [pair0: park/gather -> FWHT#2 -> epilogue+store]   (8 KB wave-private LDS)
//   [pair1: repark same LDS -> gather -> FWHT#2 -> epilogue+store]
// Pair0's stores overlap pair1's compute; B loaded once per 4 rows; P/G/S/bias
// amortized 2x vs the 2-row version. DS ops within a wave execute in order,
// so the pair1 repark (WAR on the gather reads) is safe; wave_barrier used
// as a scheduling fence.
//
// FWHT in-register (A-mapping): e[1:0]=reg[1:0], e[9:8]=reg[3:2], e[7:2]=lane.
// Cross-lane stages (all HW-verified in rounds 3/5):
//   lane^1 : DPP quad_perm [1,0,3,2]   lane^2 : DPP quad_perm [2,3,0,1]
//   lane^4 : ds_swizzle 0x101F         lane^8 : DPP row_ror:8
//   lane^16: ds_swizzle 0x401F         lane^32: __shfl_xor(v,32)
// Butterfly: v = fma(sign, v, partner), sign = -1 where the stage bit is set.

#define FF_D 1024
#define FF_STACK 4
#define FF_NT 256

#define SWZF(vf, OFF) \
    __int_as_float(__builtin_amdgcn_ds_swizzle(__float_as_int(vf), (OFF)))

// DPP move: partner = src lane permuted by CTRL; disabled-lane fallback = identity
#define DPPF(vf, CTRL) \
    __int_as_float(__builtin_amdgcn_update_dpp( \
        __float_as_int(vf), __float_as_int(vf), (CTRL), 0xF, 0xF, false))

// in-register butterfly on reg-bit m, two rows
#define STAGE_BIT2(aa, bb, m) { \
    _Pragma("unroll") \
    for (int i_ = 0; i_ < 16; ++i_) \
        if (!(i_ & (m))) { \
            float sa_ = aa[i_] + aa[i_ | (m)]; \
            float da_ = aa[i_] - aa[i_ | (m)]; \
            aa[i_] = sa_; aa[i_ | (m)] = da_; \
            float sb_ = bb[i_] + bb[i_ | (m)]; \
            float db_ = bb[i_] - bb[i_ | (m)]; \
            bb[i_] = sb_; bb[i_ | (m)] = db_; \
        } \
}

// cross-lane butterfly via DPP (VALU pipe), two rows
#define STAGE_DPP2(aa, bb, CTRL, sgn) { \
    float pa_[16], pb_[16]; \
    _Pragma("unroll") \
    for (int i_ = 0; i_ < 16; ++i_) pa_[i_] = DPPF(aa[i_], CTRL); \
    _Pragma("unroll") \
    for (int i_ = 0; i_ < 16; ++i_) pb_[i_] = DPPF(bb[i_], CTRL); \
    _Pragma("unroll") \
    for (int i_ = 0; i_ < 16; ++i_) aa[i_] = __builtin_fmaf(sgn, aa[i_], pa_[i_]); \
    _Pragma("unroll") \
    for (int i_ = 0; i_ < 16; ++i_) bb[i_] = __builtin_fmaf(sgn, bb[i_], pb_[i_]); \
}

// cross-lane butterfly via ds_swizzle (literal BitMode offset OFF), two rows
#define STAGE_SWZ2(aa, bb, OFF, sgn) { \
    float pa_[16], pb_[16]; \
    _Pragma("unroll") \
    for (int i_ = 0; i_ < 16; ++i_) pa_[i_] = SWZF(aa[i_], OFF); \
    _Pragma("unroll") \
    for (int i_ = 0; i_ < 16; ++i_) pb_[i_] = SWZF(bb[i_], OFF); \
    _Pragma("unroll") \
    for (int i_ = 0; i_ < 16; ++i_) aa[i_] = __builtin_fmaf(sgn, aa[i_], pa_[i_]); \
    _Pragma("unroll") \
    for (int i_ = 0; i_ < 16; ++i_) bb[i_] = __builtin_fmaf(sgn, bb[i_], pb_[i_]); \
}

// cross-lane butterfly on lane-xor 32, two rows
#define STAGE_X32_2(aa, bb, sgn) { \
    float pa_[16], pb_[16]; \
    _Pragma("unroll") \
    for (int i_ = 0; i_ < 16; ++i_) pa_[i_] = __shfl_xor(aa[i_], 32, 64); \
    _Pragma("unroll") \
    for (int i_ = 0; i_ < 16; ++i_) pb_[i_] = __shfl_xor(bb[i_], 32, 64); \
    _Pragma("unroll") \
    for (int i_ = 0; i_ < 16; ++i_) aa[i_] = __builtin_fmaf(sgn, aa[i_], pa_[i_]); \
    _Pragma("unroll") \
    for (int i_ = 0; i_ < 16; ++i_) bb[i_] = __builtin_fmaf(sgn, bb[i_], pb_[i_]); \
}

// full 1024-point FWHT on two rows, in registers
#define FWHT10_2(aa, bb) { \
    STAGE_BIT2(aa, bb, 1) STAGE_BIT2(aa, bb, 2) \
    STAGE_BIT2(aa, bb, 4) STAGE_BIT2(aa, bb, 8) \
    STAGE_DPP2(aa, bb, 0xB1, sg1)    /* lane^1:  quad_perm [1,0,3,2] */ \
    STAGE_DPP2(aa, bb, 0x4E, sg2)    /* lane^2:  quad_perm [2,3,0,1] */ \
    STAGE_SWZ2(aa, bb, 0x101F, sg4)  /* lane^4:  ds_swizzle          */ \
    STAGE_DPP2(aa, bb, 0x128, sg8)   /* lane^8:  row_ror:8           */ \
    STAGE_SWZ2(aa, bb, 0x401F, sg16) /* lane^16: ds_swizzle          */ \
    STAGE_X32_2(aa, bb, sg32)        /* lane^32                      */ \
}

// park two rows + gather them back through P with diag G, fused
#define PERM_PAIR(aa, bb) { \
    int4   p4_[4]; \
    float4 g4_[4]; \
    _Pragma("unroll") \
    for (int q_ = 0; q_ < 4; ++q_) { \
        const int jb_ = sb + (q_ << 8) + (lane << 2); \
        p4_[q_] = *(const int4*)&P[jb_]; \
        g4_[q_] = *(const float4*)&G[jb_]; \
    } \
    _Pragma("unroll") \
    for (int q_ = 0; q_ < 4; ++q_) { \
        const int eo_ = (q_ << 8) | (lane << 2); \
        *(float4*)&wl0[eo_] = make_float4(aa[4*q_], aa[4*q_+1], aa[4*q_+2], aa[4*q_+3]); \
        *(float4*)&wl1[eo_] = make_float4(bb[4*q_], bb[4*q_+1], bb[4*q_+2], bb[4*q_+3]); \
    } \
    __builtin_amdgcn_wave_barrier(); \
    _Pragma("unroll") \
    for (int q_ = 0; q_ < 4; ++q_) { \
        const int ix_ = p4_[q_].x & (FF_D - 1); \
        const int iy_ = p4_[q_].y & (FF_D - 1); \
        const int iz_ = p4_[q_].z & (FF_D - 1); \
        const int iw_ = p4_[q_].w & (FF_D - 1); \
        aa[4*q_+0] = wl0[ix_] * g4_[q_].x;  bb[4*q_+0] = wl1[ix_] * g4_[q_].x; \
        aa[4*q_+1] = wl0[iy_] * g4_[q_].y;  bb[4*q_+1] = wl1[iy_] * g4_[q_].y; \
        aa[4*q_+2] = wl0[iz_] * g4_[q_].z;  bb[4*q_+2] = wl1[iz_] * g4_[q_].z; \
        aa[4*q_+3] = wl0[iw_] * g4_[q_].w;  bb[4*q_+3] = wl1[iw_] * g4_[q_].w; \
    } \
}

// sincos epilogue for one element
#define CS1(val, sc, bc, bs, oC, oS) { \
    const float tr_ = __builtin_amdgcn_fractf((val) * ((sc) * karg)); \
    oC = __builtin_amdgcn_cosf(tr_) * kout + (bc); \
    oS = __builtin_amdgcn_sinf(tr_) * kout + (bs); \
}

// scale+sincos+store for a pair of rows at output bases obA, obB
#define EPILOGUE_PAIR(aa, bb, obA, obB) { \
    _Pragma("unroll") \
    for (int q_ = 0; q_ < 4; ++q_) { \
        const int j_ = sb + (q_ << 8) + (lane << 2); \
        const float4 s4_  = *(const float4*)&S[j_]; \
        const float4 bc4_ = *(const float4*)&bias[j_]; \
        const float4 bs4_ = *(const float4*)&bias[FF_STACK * FF_D + j_]; \
        float4 ocA_, osA_, ocB_, osB_; \
        CS1(aa[4*q_+0], s4_.x, bc4_.x, bs4_.x, ocA_.x, osA_.x) \
        CS1(bb[4*q_+0], s4_.x, bc4_.x, bs4_.x, ocB_.x, osB_.x) \
        CS1(aa[4*q_+1], s4_.y, bc4_.y, bs4_.y, ocA_.y, osA_.y) \
        CS1(bb[4*q_+1], s4_.y, bc4_.y, bs4_.y, ocB_.y, osB_.y) \
        CS1(aa[4*q_+2], s4_.z, bc4_.z, bs4_.z, ocA_.z, osA_.z) \
        CS1(bb[4*q_+2], s4_.z, bc4_.z, bs4_.z, ocB_.z, osB_.z) \
        CS1(aa[4*q_+3], s4_.w, bc4_.w, bs4_.w, ocA_.w, osA_.w) \
        CS1(bb[4*q_+3], s4_.w, bc4_.w, bs4_.w, ocB_.w, osB_.w) \
        *(float4*)&out[(obA) + j_] = ocA_; \
        *(float4*)&out[(obA) + FF_STACK * FF_D + j_] = osA_; \
        *(float4*)&out[(obB) + j_] = ocB_; \
        *(float4*)&out[(obB) + FF_STACK * FF_D + j_] = osB_; \
    } \
}

__global__ __launch_bounds__(FF_NT) void fastfood_kernel(
    const float* __restrict__ x,
    const float* __restrict__ Bs,
    const float* __restrict__ G,
    const float* __restrict__ S,
    const float* __restrict__ bias,
    const int*   __restrict__ P,
    float* __restrict__ out)
{
    __shared__ float lds[2 * FF_STACK * FF_D];   // 32 KB: per wave 2 row-buffers
    const int lane = threadIdx.x & 63;
    const int s    = threadIdx.x >> 6;           // stack handled by this wave
    const int row0 = blockIdx.x << 2;            // 4 rows per block
    const int sb   = s << 10;
    float* wl0 = lds + (s << 11);                // pair slot 0 (4 KB)
    float* wl1 = wl0 + FF_D;                     // pair slot 1 (4 KB)

    // butterfly signs per lane-stage: -1 where the lane's stage bit is set
    const float sg1  = (lane & 1)  ? -1.0f : 1.0f;
    const float sg2  = (lane & 2)  ? -1.0f : 1.0f;
    const float sg4  = (lane & 4)  ? -1.0f : 1.0f;
    const float sg8  = (lane & 8)  ? -1.0f : 1.0f;
    const float sg16 = (lane & 16) ? -1.0f : 1.0f;
    const float sg32 = (lane & 32) ? -1.0f : 1.0f;

    const float kout = 0.03125f;                      // 1/sqrt(1024)
    const float karg = 0.03125f * 0.15915494309f;     // /(2*pi): revolutions

    float a0[16], a1[16], a2[16], a3[16];

    // ---- load 4 rows (A mapping), fused with diag B (loaded once) ----
    const long long xb = ((long long)row0 << 10);
    #pragma unroll
    for (int q = 0; q < 4; ++q) {
        const int eo = (q << 8) + (lane << 2);
        const float4 b4 = *(const float4*)&Bs[sb + eo];
        const float4 t0 = *(const float4*)&x[xb + eo];
        const float4 t1 = *(const float4*)&x[xb + FF_D + eo];
        const float4 t2 = *(const float4*)&x[xb + 2 * FF_D + eo];
        const float4 t3 = *(const float4*)&x[xb + 3 * FF_D + eo];
        a0[4*q+0] = t0.x * b4.x; a0[4*q+1] = t0.y * b4.y;
        a0[4*q+2] = t0.z * b4.z; a0[4*q+3] = t0.w * b4.w;
        a1[4*q+0] = t1.x * b4.x; a1[4*q+1] = t1.y * b4.y;
        a1[4*q+2] = t1.z * b4.z; a1[4*q+3] = t1.w * b4.w;
        a2[4*q+0] = t2.x * b4.x; a2[4*q+1] = t2.y * b4.y;
        a2[4*q+2] = t2.z * b4.z; a2[4*q+3] = t2.w * b4.w;
        a3[4*q+0] = t3.x * b4.x; a3[4*q+1] = t3.y * b4.y;
        a3[4*q+2] = t3.z * b4.z; a3[4*q+3] = t3.w * b4.w;
    }

    // ---------- FWHT #1 on all four rows (4 independent chains) ----------
    FWHT10_2(a0, a1)
    FWHT10_2(a2, a3)

    const long long ob = ((long long)row0 << 13);     // row0 * 8192
    const long long RB = FF_STACK * FF_D * 2;         // 8192 (row stride in out)

    // ---------- pair 0: rows 0,1 ----------
    PERM_PAIR(a0, a1)
    FWHT10_2(a0, a1)
    EPILOGUE_PAIR(a0, a1, ob, ob + RB)

    // ---------- pair 1: rows 2,3 (reuse the wave-private LDS slots) ----------
    __builtin_amdgcn_wave_barrier();   // fence: repark after pair0 gather
    PERM_PAIR(a2, a3)
    FWHT10_2(a2, a3)
    EPILOGUE_PAIR(a2, a3, ob + 2 * RB, ob + 3 * RB)
}

extern "C" void kernel_launch(void* const* d_in, const int* in_sizes, int n_in,
                              void* d_out, int out_size, void* d_ws, size_t ws_size,
                              hipStream_t stream) {
    // setup_inputs order: x, B, G, S, bias, H, P   (H unused: FWHT instead)
    const float* x    = (const float*)d_in[0];
    const float* B    = (const float*)d_in[1];
    const float* G    = (const float*)d_in[2];
    const float* S    = (const float*)d_in[3];
    const float* bias = (const float*)d_in[4];
    const int*   P    = (const int*)d_in[6];
    float* out = (float*)d_out;

    const int n_rows = in_sizes[0] / FF_D;   // 8192
    fastfood_kernel<<<n_rows / 4, FF_NT, 0, stream>>>(x, B, G, S, bias, P, out);
}